// Round 14
// baseline (313.405 us; speedup 1.0000x reference)
//
#include <hip/hip_runtime.h>
#include <hip/hip_bf16.h>

typedef __hip_bfloat16 bf16;
typedef __attribute__((ext_vector_type(8))) short short8;
typedef __attribute__((ext_vector_type(4))) float f32x4;
typedef __attribute__((ext_vector_type(4))) unsigned short ushort4v;

#define DEV static __device__ __forceinline__

static constexpr int SEQ = 2048;
static constexpr int DM  = 1024;
static constexpr int NH  = 16;
static constexpr int HD  = 64;
static constexpr int WIN = 2048;
static constexpr int PAD = 1024;   // WIN/2

// async global->LDS, 16B per lane; LDS dest = wave-uniform base + lane*16
DEV void async16(const void* g, void* l) {
  __builtin_amdgcn_global_load_lds(
      (__attribute__((address_space(1))) void*)(g),
      (__attribute__((address_space(3))) void*)(l), 16, 0, 0);
}

// ---------------------------------------------------------------- K0: f32 -> bf16 convert (x, w_qkv, w_proj)
__global__ __launch_bounds__(256) void k_cvt(const float* __restrict__ x,
                                             const float* __restrict__ wq,
                                             const float* __restrict__ wp,
                                             bf16* __restrict__ xb,
                                             bf16* __restrict__ wqb,
                                             bf16* __restrict__ wpb) {
  const int NX = SEQ * DM, NQ = 3 * DM * DM, NP = DM * DM;
  const int tot = (NX + NQ + NP) >> 2;
  const int stride = gridDim.x * 256;
  for (int i = blockIdx.x * 256 + threadIdx.x; i < tot; i += stride) {
    int e = i << 2;
    const float* s; bf16* d; int o;
    if (e < NX)            { s = x;  d = xb;  o = e; }
    else if (e < NX + NQ)  { s = wq; d = wqb; o = e - NX; }
    else                   { s = wp; d = wpb; o = e - NX - NQ; }
    float4 v = *(const float4*)(s + o);
    __align__(8) bf16 t4[4] = {__float2bfloat16(v.x), __float2bfloat16(v.y),
                               __float2bfloat16(v.z), __float2bfloat16(v.w)};
    *(uint2*)(d + o) = *(uint2*)t4;
  }
}

// ---------------------------------------------------------------- 64x128 GEMM core: C[m][n] = sum_k A[m][k]*B[n][k]
// 256 threads = 4 waves, each wave owns 64m x 32n (acc[4][2]); BK=64.
DEV void gemm_core64(const bf16* __restrict__ A, const bf16* __restrict__ B,
                     int m0, int n0, int K, int tid, bf16* As, bf16* Bs,
                     f32x4 (&acc)[4][2]) {
  const int lane = tid & 63, wid = tid >> 6;   // wid = n-group (0..3)
  const int l15 = lane & 15, l4 = lane >> 4;
  for (int k0 = 0; k0 < K; k0 += 64) {
    __syncthreads();
    #pragma unroll
    for (int it = 0; it < 2; ++it) {           // A: 64 rows
      int rb = it * 32 + wid * 8;
      int r  = rb + (lane >> 3);
      int c  = (lane & 7) * 8;
      async16(A + (size_t)(m0 + r) * K + k0 + c, As + rb * 64);
    }
    #pragma unroll
    for (int it = 0; it < 4; ++it) {           // B: 128 rows
      int rb = it * 32 + wid * 8;
      int r  = rb + (lane >> 3);
      int c  = (lane & 7) * 8;
      async16(B + (size_t)(n0 + r) * K + k0 + c, Bs + rb * 64);
    }
    asm volatile("s_waitcnt vmcnt(0)" ::: "memory");
    __syncthreads();
    #pragma unroll
    for (int kk = 0; kk < 2; ++kk) {
      short8 a[4], b[2];
      #pragma unroll
      for (int im = 0; im < 4; ++im)
        a[im] = *(const short8*)(As + (im * 16 + l15) * 64 + kk * 32 + l4 * 8);
      #pragma unroll
      for (int in = 0; in < 2; ++in)
        b[in] = *(const short8*)(Bs + (wid * 32 + in * 16 + l15) * 64 + kk * 32 + l4 * 8);
      #pragma unroll
      for (int im = 0; im < 4; ++im)
        #pragma unroll
        for (int in = 0; in < 2; ++in)
          acc[im][in] = __builtin_amdgcn_mfma_f32_16x16x32_bf16(a[im], b[in], acc[im][in], 0, 0, 0);
    }
  }
}

// ---------------------------------------------------------------- K1: qkv GEMM (64x128 tiles) + scatter to q/k/vT
__global__ __launch_bounds__(256) void k_gemm_qkv(const bf16* __restrict__ A,
                                                  const bf16* __restrict__ B,
                                                  const float* __restrict__ bias,
                                                  bf16* __restrict__ qo,
                                                  bf16* __restrict__ ko,
                                                  bf16* __restrict__ vt) {
  __shared__ bf16 As[64 * 64], Bs[128 * 64];
  const int tid = threadIdx.x, lane = tid & 63;
  const int wid = tid >> 6;
  const int l15 = lane & 15, l4 = lane >> 4;
  const int m0 = blockIdx.x * 64, n0 = blockIdx.y * 128;
  f32x4 acc[4][2] = {};
  gemm_core64(A, B, m0, n0, DM, tid, As, Bs, acc);
  #pragma unroll
  for (int im = 0; im < 4; ++im)
    #pragma unroll
    for (int in = 0; in < 2; ++in) {
      int col = n0 + wid * 32 + in * 16 + l15;
      float bval = bias[col];
      int t = col >> 10, h = (col >> 6) & 15, dd = col & 63;
      int row0 = m0 + im * 16 + l4 * 4;
      if (t == 2) {
        // v transposed directly: vT[h][dd][j], 4 consecutive j -> one 8B store
        __align__(8) bf16 t4[4];
        #pragma unroll
        for (int r = 0; r < 4; ++r)
          t4[r] = __float2bfloat16(acc[im][in][r] + bval);
        *(uint2*)&vt[((size_t)h * HD + dd) * SEQ + row0] = *(uint2*)t4;
      } else {
        #pragma unroll
        for (int r = 0; r < 4; ++r) {
          float v = acc[im][in][r] + bval;
          size_t idx = ((size_t)h * SEQ + row0 + r) * HD + dd;
          // q folded with hd^-0.5 * log2(e) so scores feed exp2 directly
          if (t == 0) qo[idx] = __float2bfloat16(v * 0.18033688011112042f);
          else        ko[idx] = __float2bfloat16(v);
        }
      }
    }
}

// ---------------------------------------------------------------- attn helpers
DEV void stage_kp(const bf16* kbase, int i0, int tt, int lane, bf16* dst) {
  #pragma unroll
  for (int it = 0; it < 4; ++it) {
    int r  = it * 8 + (lane >> 3);
    int cg = lane & 7;
    int jp = i0 + tt * 32 + r;                 // absolute j'
    int krow = jp - PAD;                       // clamp; pad handled analytically
    krow = krow < 0 ? 0 : (krow > SEQ - 1 ? SEQ - 1 : krow);
    int sc = (cg ^ (r & 7)) * 8;               // pre-swizzled global source
    async16(kbase + (size_t)krow * HD + sc, dst + it * 8 * 64);
  }
}

// LDS K -> MFMA, unswapped: sf[fm][fn]: col=j'(l15), row=i(l4*4+r)
DEV void qk_mfma_lds(const bf16* KPb, const short8 (&qf)[2][2], int l15, int l4,
                     f32x4 (&sf)[2][2]) {
  __builtin_amdgcn_s_setprio(1);
  #pragma unroll
  for (int kg = 0; kg < 2; ++kg) {
    short8 kfr[2];
    #pragma unroll
    for (int fn = 0; fn < 2; ++fn) {
      int jl = fn * 16 + l15;
      int pg = (kg * 4 + l4) ^ (jl & 7);
      kfr[fn] = *(const short8*)&KPb[jl * 64 + pg * 8];
    }
    #pragma unroll
    for (int fm = 0; fm < 2; ++fm)
      #pragma unroll
      for (int fn = 0; fn < 2; ++fn)
        sf[fm][fn] = __builtin_amdgcn_mfma_f32_16x16x32_bf16(qf[fm][kg], kfr[fn], sf[fm][fn], 0, 0, 0);
  }
  __builtin_amdgcn_s_setprio(0);
}

// swapped variant (phase 1): sf[fj][fi]: col=i(l15), row=j'(l4*4+r)
DEV void qk_mfma_lds_sw(const bf16* KPb, const short8 (&qf)[2][2], int l15, int l4,
                        f32x4 (&sf)[2][2]) {
  __builtin_amdgcn_s_setprio(1);
  #pragma unroll
  for (int kg = 0; kg < 2; ++kg) {
    short8 kfr[2];
    #pragma unroll
    for (int fj = 0; fj < 2; ++fj) {
      int jl = fj * 16 + l15;
      int pg = (kg * 4 + l4) ^ (jl & 7);
      kfr[fj] = *(const short8*)&KPb[jl * 64 + pg * 8];
    }
    #pragma unroll
    for (int fj = 0; fj < 2; ++fj)
      #pragma unroll
      for (int fi = 0; fi < 2; ++fi)
        sf[fj][fi] = __builtin_amdgcn_mfma_f32_16x16x32_bf16(kfr[fj], qf[fi][kg], sf[fj][fi], 0, 0, 0);
  }
  __builtin_amdgcn_s_setprio(0);
}

DEV int pad_lo(int i0) { int d = PAD - i0; return d <= 0 ? 0 : (d >> 5); }
DEV int pad_hi(int i0) { int t = ((PAD + SEQ - 1 - i0) >> 5) + 1; return t > 65 ? 65 : t; }

// ---------------------------------------------------------------- K2: merged attn, 33KB LDS union -> 4 blocks/CU
// block = (h, i0) via XCD swizzle; 4 chunk-waves. Phase 1: gload_lds dbuf (8KB/wave
// union slice). Phase 2: single 4KB KP + T14 reg-prefetch + 4KB raw-e ring.
__global__ __launch_bounds__(256, 4) void k_attn(const bf16* __restrict__ q,
                                                 const bf16* __restrict__ kkk,
                                                 const bf16* __restrict__ vT,
                                                 float* __restrict__ attn,
                                                 bf16* __restrict__ ao) {
  // XCD-aware bijective swizzle (1024 % 8 == 0)
  const int wgid = (blockIdx.x & 7) * 128 + (blockIdx.x >> 3);
  const int h  = wgid >> 6;
  const int i0 = (wgid & 63) << 5;
  const int tid = threadIdx.x;
  const int c = tid >> 6;                     // wave = chunk
  const int lane = tid & 63;
  const int l15 = lane & 15, l4 = lane >> 4;
  const int lo_g = pad_lo(i0), hi_g = pad_hi(i0);

  __shared__ __align__(16) bf16 UB[4 * 4096]; // 32 KB union (per-wave 8KB slice)
  __shared__ float sums[4][32];
  __shared__ float invL[32];

  short8 qf[2][2];
  #pragma unroll
  for (int fm = 0; fm < 2; ++fm)
    #pragma unroll
    for (int kg = 0; kg < 2; ++kg)
      qf[fm][kg] = *(const short8*)&q[((size_t)h * SEQ + i0 + fm * 16 + l15) * HD + kg * 32 + l4 * 8];

  const bf16* kbase = kkk + (size_t)h * SEQ * HD;
  const bf16* vbase = vT + (size_t)h * HD * SEQ;
  float* abase = attn + (size_t)(h * SEQ + i0) * WIN;

  // ---------------- phase 1: partial exp-sums (swapped QK), gload_lds double buffer
  {
    bf16* B0 = UB + c * 4096;
    bf16* B1 = UB + c * 4096 + 2048;
    constexpr int st[5] = {0, 16, 32, 48, 65};
    int lo = st[c] > lo_g ? st[c] : lo_g;
    int hi = st[c + 1] < hi_g ? st[c + 1] : hi_g;

    float psum[2] = {0.f, 0.f};
    if (lo < hi) {
      stage_kp(kbase, i0, lo, lane, (lo & 1) ? B1 : B0);
      for (int tt = lo; tt < hi; ++tt) {
        int nxt = (tt + 1 < hi) ? tt + 1 : tt;
        stage_kp(kbase, i0, nxt, lane, ((tt + 1) & 1) ? B1 : B0);
        asm volatile("s_waitcnt vmcnt(4)" ::: "memory");
        f32x4 sf[2][2] = {};
        qk_mfma_lds_sw((tt & 1) ? B1 : B0, qf, l15, l4, sf);
        const bool interior = (tt >= 1) && (tt <= 63) &&
                              (i0 + tt * 32 >= PAD) && (i0 + tt * 32 + 31 < PAD + SEQ);
        if (interior) {
          #pragma unroll
          for (int fj = 0; fj < 2; ++fj)
            #pragma unroll
            for (int r = 0; r < 4; ++r) {
              psum[0] += __builtin_amdgcn_exp2f(sf[fj][0][r]);
              psum[1] += __builtin_amdgcn_exp2f(sf[fj][1][r]);
            }
        } else {
          #pragma unroll
          for (int fj = 0; fj < 2; ++fj)
            #pragma unroll
            for (int r = 0; r < 4; ++r) {
              int jj = tt * 32 + fj * 16 + l4 * 4 + r;   // local j'
              int jp = i0 + jj;                          // absolute j'
              bool pad = (jp < PAD) || (jp >= PAD + SEQ);
              #pragma unroll
              for (int fi = 0; fi < 2; ++fi) {
                int iloc = fi * 16 + l15;
                float e = pad ? 1.0f : __builtin_amdgcn_exp2f(sf[fj][fi][r]);
                if ((unsigned)(jj - iloc) < (unsigned)WIN) psum[fi] += e;
              }
            }
        }
      }
    }
    float r0 = psum[0];
    r0 += __shfl_xor(r0, 16); r0 += __shfl_xor(r0, 32);
    float r1 = psum[1];
    r1 += __shfl_xor(r1, 16); r1 += __shfl_xor(r1, 32);
    if (lane < 32) {
      int i_abs = i0 + lane;
      float s = (lane < 16) ? r0 : r1;
      if (c == 0) {
        int cl = i0 + lo_g * 32 - i_abs; if (cl < 0) cl = 0;
        int cr = i_abs + WIN - (i0 + hi_g * 32); if (cr < 0) cr = 0;
        s += (float)(cl + cr);                  // analytic all-pad contribution
      }
      sums[c][lane] = s;
    }
  }
  __syncthreads();
  if (tid < 32)
    invL[tid] = __builtin_amdgcn_rcpf(sums[0][tid] + sums[1][tid] +
                                      sums[2][tid] + sums[3][tid]);
  __syncthreads();

  // per-lane flush inverses (row = s2*8 + (lane>>3))
  float invf[4];
  #pragma unroll
  for (int s2 = 0; s2 < 4; ++s2) invf[s2] = invL[s2 * 8 + (lane >> 3)];

  // ---------------- phase 2: single-KP + reg-prefetch staging, raw-e rebin, flush, PV
  const int c0 = c * 16, c1 = c0 + 16;
  bf16* KPc = UB + c * 4096;                  // 2048 bf16 (4 KB)
  unsigned short* JW = (unsigned short*)(UB + c * 4096 + 2048);  // 4 KB ring

  // prologue: stage tile c0 through registers
  {
    short8 kr[4];
    #pragma unroll
    for (int it = 0; it < 4; ++it) {
      int r = it * 8 + (lane >> 3), cg = lane & 7;
      int jp = i0 + c0 * 32 + r;
      int krow = jp - PAD;
      krow = krow < 0 ? 0 : (krow > SEQ - 1 ? SEQ - 1 : krow);
      kr[it] = *(const short8*)&kbase[(size_t)krow * HD + (cg ^ (r & 7)) * 8];
    }
    #pragma unroll
    for (int it = 0; it < 4; ++it)
      *(short8*)&KPc[it * 512 + lane * 8] = kr[it];
  }

  f32x4 oacc[2][4] = {};
  for (int tt = c0; tt <= c1; ++tt) {
    // T14 issue-early: prefetch tile tt+1 into registers (latency hides under body)
    short8 krn[4];
    if (tt < c1) {
      #pragma unroll
      for (int it = 0; it < 4; ++it) {
        int r = it * 8 + (lane >> 3), cg = lane & 7;
        int jp = i0 + (tt + 1) * 32 + r;
        int krow = jp - PAD;
        krow = krow < 0 ? 0 : (krow > SEQ - 1 ? SEQ - 1 : krow);
        krn[it] = *(const short8*)&kbase[(size_t)krow * HD + (cg ^ (r & 7)) * 8];
      }
    }
    short8 bv[4];
    if (tt > c0) {
      int jb = (tt - 1) * 32;
      #pragma unroll
      for (int nd = 0; nd < 4; ++nd)
        bv[nd] = *(const short8*)&vbase[(size_t)(nd * 16 + l15) * SEQ + jb + l4 * 8];
    }

    const bool fp = (tt < lo_g) || (tt >= hi_g);   // all-pad tile: score==0 -> e=1
    f32x4 sf[2][2] = {};
    if (!fp) qk_mfma_lds(KPc, qf, l15, l4, sf);

    // re-bin raw e (bf16) into j-aligned ring; 16B-group swizzle sg=(j6>>3)^(row&7)
    const bool allv = (i0 + tt * 32 >= PAD) && (i0 + tt * 32 + 31 < PAD + SEQ);
    #pragma unroll
    for (int fm = 0; fm < 2; ++fm)
      #pragma unroll
      for (int fn = 0; fn < 2; ++fn) {
        int J0 = tt * 32 + fn * 16 + l15;          // local j' (col)
        bool padc = fp || (!allv && ((i0 + J0 < PAD) || (i0 + J0 >= PAD + SEQ)));
        #pragma unroll
        for (int r = 0; r < 4; ++r) {
          int row = fm * 16 + l4 * 4 + r;          // local i
          float e = padc ? 1.0f : __builtin_amdgcn_exp2f(sf[fm][fn][r]);
          int j6 = (J0 - row) & 63;                // ring position
          int sg = (j6 >> 3) ^ (row & 7);
          JW[row * 64 + sg * 8 + (j6 & 7)] = __bfloat16_as_ushort(__float2bfloat16(e));
        }
      }

    if (tt > c0) {
      const int g = (tt - 1) & 1;                  // ring slot of completed j-tile
      const int Jb = (tt - 1) * 32;
      const int c8 = lane & 7;
      // flush: normalize raw e with invL at store time; full-128B-line stores
      #pragma unroll
      for (int s2 = 0; s2 < 4; ++s2) {
        int row = s2 * 8 + (lane >> 3);
        int sg = (g * 4 + (c8 >> 1)) ^ (row & 7);
        ushort4v uv = *(const ushort4v*)&JW[row * 64 + sg * 8 + (c8 & 1) * 4];
        f32x4 vv;
        #pragma unroll
        for (int e = 0; e < 4; ++e)
          vv[e] = __uint_as_float((unsigned)uv[e] << 16) * invf[s2];
        *(f32x4*)(abase + (size_t)row * WIN + Jb + c8 * 4) = vv;
      }
      // PV A-fragments: raw e, 16B contiguous per lane
      short8 af[2];
      #pragma unroll
      for (int fm = 0; fm < 2; ++fm) {
        int row = fm * 16 + l15;
        int sg = (g * 4 + l4) ^ (row & 7);
        af[fm] = *(const short8*)&JW[row * 64 + sg * 8];
      }
      __builtin_amdgcn_s_setprio(1);
      #pragma unroll
      for (int fm = 0; fm < 2; ++fm)
        #pragma unroll
        for (int nd = 0; nd < 4; ++nd)
          oacc[fm][nd] = __builtin_amdgcn_mfma_f32_16x16x32_bf16(af[fm], bv[nd], oacc[fm][nd], 0, 0, 0);
      __builtin_amdgcn_s_setprio(0);
    }

    // T14 write-late: stage prefetched tile into KPc (all KPc reads of this iter done)
    if (tt < c1) {
      #pragma unroll
      for (int it = 0; it < 4; ++it)
        *(short8*)&KPc[it * 512 + lane * 8] = krn[it];
    }
  }

  // ---------------- in-block O reduction in f32 via union buffer; scale by invL
  __syncthreads();                              // all PV/ring reads drained
  float* OX = (float*)UB;                       // 32 KB = 4 waves x 2048 f32
  float* OW = OX + c * 2048;
  #pragma unroll
  for (int fm = 0; fm < 2; ++fm)
    #pragma unroll
    for (int nd = 0; nd < 4; ++nd)
      #pragma unroll
      for (int r = 0; r < 4; ++r)
        OW[(fm * 16 + l4 * 4 + r) * 64 + nd * 16 + l15] = oacc[fm][nd][r];
  __syncthreads();
  {
    int row = tid >> 3;
    int d0 = (tid & 7) * 8;
    float iv = invL[row];
    union { unsigned short u[8]; short8 v; } o;
    #pragma unroll
    for (int e = 0; e < 8; ++e) {
      int idx = row * 64 + d0 + e;
      float s = (OX[idx] + OX[2048 + idx] + OX[4096 + idx] + OX[6144 + idx]) * iv;
      o.u[e] = __bfloat16_as_ushort(__float2bfloat16(s));
    }
    *(short8*)&ao[(size_t)(i0 + row) * DM + h * HD + d0] = o.v;
  }
}

// ---------------------------------------------------------------- K4: proj GEMM (64x128 tiles) -> d_out (f32)
__global__ __launch_bounds__(256) void k_gemm_proj(const bf16* __restrict__ A,
                                                   const bf16* __restrict__ B,
                                                   const float* __restrict__ bias,
                                                   float* __restrict__ out) {
  __shared__ bf16 As[64 * 64], Bs[128 * 64];
  const int tid = threadIdx.x, lane = tid & 63;
  const int wid = tid >> 6;
  const int l15 = lane & 15, l4 = lane >> 4;
  const int m0 = blockIdx.x * 64, n0 = blockIdx.y * 128;
  f32x4 acc[4][2] = {};
  gemm_core64(A, B, m0, n0, DM, tid, As, Bs, acc);
  #pragma unroll
  for (int im = 0; im < 4; ++im)
    #pragma unroll
    for (int in = 0; in < 2; ++in) {
      int col = n0 + wid * 32 + in * 16 + l15;
      float bval = bias[col];
      #pragma unroll
      for (int r = 0; r < 4; ++r) {
        int row = m0 + im * 16 + l4 * 4 + r;
        out[(size_t)row * DM + col] = acc[im][in][r] + bval;
      }
    }
}

// ---------------------------------------------------------------- launch
extern "C" void kernel_launch(void* const* d_in, const int* in_sizes, int n_in,
                              void* d_out, int out_size, void* d_ws, size_t ws_size,
                              hipStream_t stream) {
  (void)in_sizes; (void)n_in; (void)out_size; (void)ws_size;
  const float* x  = (const float*)d_in[0];
  const float* wq = (const float*)d_in[1];
  const float* bq = (const float*)d_in[2];
  const float* wp = (const float*)d_in[3];
  const float* bp = (const float*)d_in[4];
  float* out  = (float*)d_out;
  float* attn = out + (size_t)SEQ * DM;

  char* ws = (char*)d_ws;
  bf16* xb    = (bf16*)(ws + (size_t) 0);          // 4 MB  x bf16
  bf16* wqb   = (bf16*)(ws + ((size_t)4  << 20));  // 6 MB  w_qkv bf16
  bf16* wpb   = (bf16*)(ws + ((size_t)10 << 20));  // 2 MB  w_proj bf16
  bf16* qarr  = (bf16*)(ws + ((size_t)12 << 20));  // 4 MB  q [h][i][d] (scale*log2e folded)
  bf16* karr  = (bf16*)(ws + ((size_t)16 << 20));  // 4 MB  k [h][j][d]
  bf16* vt    = (bf16*)(ws + ((size_t)24 << 20));  // 4 MB  vT [h][d][j] (qkv epilogue)
  bf16* ao    = (bf16*)(ws + ((size_t)28 << 20));  // 4 MB  attn-out rows [i][h*64+d]

  k_cvt<<<dim3(1024), dim3(256), 0, stream>>>(x, wq, wp, xb, wqb, wpb);
  k_gemm_qkv<<<dim3(32, 24), dim3(256), 0, stream>>>(xb, wqb, bq, qarr, karr, vt);
  k_attn<<<dim3(1024), dim3(256), 0, stream>>>(qarr, karr, vt, attn, ao);
  k_gemm_proj<<<dim3(32, 8), dim3(256), 0, stream>>>(ao, wpb, bp, out);
}

// Round 15
// 155.221 us; speedup vs baseline: 2.0191x; 2.0191x over previous
//
#include <hip/hip_runtime.h>
#include <hip/hip_bf16.h>

typedef __hip_bfloat16 bf16;
typedef __attribute__((ext_vector_type(8))) short short8;
typedef __attribute__((ext_vector_type(4))) float f32x4;
typedef __attribute__((ext_vector_type(4))) unsigned short ushort4v;

#define DEV static __device__ __forceinline__

static constexpr int SEQ = 2048;
static constexpr int DM  = 1024;
static constexpr int NH  = 16;
static constexpr int HD  = 64;
static constexpr int WIN = 2048;
static constexpr int PAD = 1024;   // WIN/2

// async global->LDS, 16B per lane; LDS dest = wave-uniform base + lane*16
DEV void async16(const void* g, void* l) {
  __builtin_amdgcn_global_load_lds(
      (__attribute__((address_space(1))) void*)(g),
      (__attribute__((address_space(3))) void*)(l), 16, 0, 0);
}

// ---------------------------------------------------------------- K0: f32 -> bf16 convert (x, w_qkv, w_proj)
__global__ __launch_bounds__(256) void k_cvt(const float* __restrict__ x,
                                             const float* __restrict__ wq,
                                             const float* __restrict__ wp,
                                             bf16* __restrict__ xb,
                                             bf16* __restrict__ wqb,
                                             bf16* __restrict__ wpb) {
  const int NX = SEQ * DM, NQ = 3 * DM * DM, NP = DM * DM;
  const int tot = (NX + NQ + NP) >> 2;
  const int stride = gridDim.x * 256;
  for (int i = blockIdx.x * 256 + threadIdx.x; i < tot; i += stride) {
    int e = i << 2;
    const float* s; bf16* d; int o;
    if (e < NX)            { s = x;  d = xb;  o = e; }
    else if (e < NX + NQ)  { s = wq; d = wqb; o = e - NX; }
    else                   { s = wp; d = wpb; o = e - NX - NQ; }
    float4 v = *(const float4*)(s + o);
    __align__(8) bf16 t4[4] = {__float2bfloat16(v.x), __float2bfloat16(v.y),
                               __float2bfloat16(v.z), __float2bfloat16(v.w)};
    *(uint2*)(d + o) = *(uint2*)t4;
  }
}

// ---------------------------------------------------------------- 64x128 GEMM core: C[m][n] = sum_k A[m][k]*B[n][k]
DEV void gemm_core64(const bf16* __restrict__ A, const bf16* __restrict__ B,
                     int m0, int n0, int K, int tid, bf16* As, bf16* Bs,
                     f32x4 (&acc)[4][2]) {
  const int lane = tid & 63, wid = tid >> 6;   // wid = n-group (0..3)
  const int l15 = lane & 15, l4 = lane >> 4;
  for (int k0 = 0; k0 < K; k0 += 64) {
    __syncthreads();
    #pragma unroll
    for (int it = 0; it < 2; ++it) {           // A: 64 rows
      int rb = it * 32 + wid * 8;
      int r  = rb + (lane >> 3);
      int c  = (lane & 7) * 8;
      async16(A + (size_t)(m0 + r) * K + k0 + c, As + rb * 64);
    }
    #pragma unroll
    for (int it = 0; it < 4; ++it) {           // B: 128 rows
      int rb = it * 32 + wid * 8;
      int r  = rb + (lane >> 3);
      int c  = (lane & 7) * 8;
      async16(B + (size_t)(n0 + r) * K + k0 + c, Bs + rb * 64);
    }
    asm volatile("s_waitcnt vmcnt(0)" ::: "memory");
    __syncthreads();
    #pragma unroll
    for (int kk = 0; kk < 2; ++kk) {
      short8 a[4], b[2];
      #pragma unroll
      for (int im = 0; im < 4; ++im)
        a[im] = *(const short8*)(As + (im * 16 + l15) * 64 + kk * 32 + l4 * 8);
      #pragma unroll
      for (int in = 0; in < 2; ++in)
        b[in] = *(const short8*)(Bs + (wid * 32 + in * 16 + l15) * 64 + kk * 32 + l4 * 8);
      #pragma unroll
      for (int im = 0; im < 4; ++im)
        #pragma unroll
        for (int in = 0; in < 2; ++in)
          acc[im][in] = __builtin_amdgcn_mfma_f32_16x16x32_bf16(a[im], b[in], acc[im][in], 0, 0, 0);
    }
  }
}

// ---------------------------------------------------------------- K1: qkv GEMM (64x128 tiles) + scatter to q/k/vT
__global__ __launch_bounds__(256) void k_gemm_qkv(const bf16* __restrict__ A,
                                                  const bf16* __restrict__ B,
                                                  const float* __restrict__ bias,
                                                  bf16* __restrict__ qo,
                                                  bf16* __restrict__ ko,
                                                  bf16* __restrict__ vt) {
  __shared__ bf16 As[64 * 64], Bs[128 * 64];
  const int tid = threadIdx.x, lane = tid & 63;
  const int wid = tid >> 6;
  const int l15 = lane & 15, l4 = lane >> 4;
  const int m0 = blockIdx.x * 64, n0 = blockIdx.y * 128;
  f32x4 acc[4][2] = {};
  gemm_core64(A, B, m0, n0, DM, tid, As, Bs, acc);
  #pragma unroll
  for (int im = 0; im < 4; ++im)
    #pragma unroll
    for (int in = 0; in < 2; ++in) {
      int col = n0 + wid * 32 + in * 16 + l15;
      float bval = bias[col];
      int t = col >> 10, h = (col >> 6) & 15, dd = col & 63;
      int row0 = m0 + im * 16 + l4 * 4;
      if (t == 2) {
        __align__(8) bf16 t4[4];
        #pragma unroll
        for (int r = 0; r < 4; ++r)
          t4[r] = __float2bfloat16(acc[im][in][r] + bval);
        *(uint2*)&vt[((size_t)h * HD + dd) * SEQ + row0] = *(uint2*)t4;
      } else {
        #pragma unroll
        for (int r = 0; r < 4; ++r) {
          float v = acc[im][in][r] + bval;
          size_t idx = ((size_t)h * SEQ + row0 + r) * HD + dd;
          // q folded with hd^-0.5 * log2(e) so scores feed exp2 directly
          if (t == 0) qo[idx] = __float2bfloat16(v * 0.18033688011112042f);
          else        ko[idx] = __float2bfloat16(v);
        }
      }
    }
}

// ---------------------------------------------------------------- attn helpers
DEV void stage_kp(const bf16* kbase, int i0, int tt, int lane, bf16* dst) {
  #pragma unroll
  for (int it = 0; it < 4; ++it) {
    int r  = it * 8 + (lane >> 3);
    int cg = lane & 7;
    int jp = i0 + tt * 32 + r;                 // absolute j'
    int krow = jp - PAD;                       // clamp; pad handled analytically
    krow = krow < 0 ? 0 : (krow > SEQ - 1 ? SEQ - 1 : krow);
    int sc = (cg ^ (r & 7)) * 8;               // pre-swizzled global source
    async16(kbase + (size_t)krow * HD + sc, dst + it * 8 * 64);
  }
}

// LDS K -> MFMA, unswapped: sf[fm][fn]: col=j'(l15), row=i(l4*4+r)
DEV void qk_mfma_lds(const bf16* KPb, const short8 (&qf)[2][2], int l15, int l4,
                     f32x4 (&sf)[2][2]) {
  __builtin_amdgcn_s_setprio(1);
  #pragma unroll
  for (int kg = 0; kg < 2; ++kg) {
    short8 kfr[2];
    #pragma unroll
    for (int fn = 0; fn < 2; ++fn) {
      int jl = fn * 16 + l15;
      int pg = (kg * 4 + l4) ^ (jl & 7);
      kfr[fn] = *(const short8*)&KPb[jl * 64 + pg * 8];
    }
    #pragma unroll
    for (int fm = 0; fm < 2; ++fm)
      #pragma unroll
      for (int fn = 0; fn < 2; ++fn)
        sf[fm][fn] = __builtin_amdgcn_mfma_f32_16x16x32_bf16(qf[fm][kg], kfr[fn], sf[fm][fn], 0, 0, 0);
  }
  __builtin_amdgcn_s_setprio(0);
}

// swapped variant (phase 1): sf[fj][fi]: col=i(l15), row=j'(l4*4+r)
DEV void qk_mfma_lds_sw(const bf16* KPb, const short8 (&qf)[2][2], int l15, int l4,
                        f32x4 (&sf)[2][2]) {
  __builtin_amdgcn_s_setprio(1);
  #pragma unroll
  for (int kg = 0; kg < 2; ++kg) {
    short8 kfr[2];
    #pragma unroll
    for (int fj = 0; fj < 2; ++fj) {
      int jl = fj * 16 + l15;
      int pg = (kg * 4 + l4) ^ (jl & 7);
      kfr[fj] = *(const short8*)&KPb[jl * 64 + pg * 8];
    }
    #pragma unroll
    for (int fj = 0; fj < 2; ++fj)
      #pragma unroll
      for (int fi = 0; fi < 2; ++fi)
        sf[fj][fi] = __builtin_amdgcn_mfma_f32_16x16x32_bf16(kfr[fj], qf[fi][kg], sf[fj][fi], 0, 0, 0);
  }
  __builtin_amdgcn_s_setprio(0);
}

DEV int pad_lo(int i0) { int d = PAD - i0; return d <= 0 ? 0 : (d >> 5); }
DEV int pad_hi(int i0) { int t = ((PAD + SEQ - 1 - i0) >> 5) + 1; return t > 65 ? 65 : t; }

// ---------------------------------------------------------------- K2: merged attn, 64 rows/block
// 4 waves = 2 row-tiles x 2 window-halves; grid 512 = 2 blocks/CU, zero tail.
__global__ __launch_bounds__(256) void k_attn(const bf16* __restrict__ q,
                                              const bf16* __restrict__ kkk,
                                              const bf16* __restrict__ vT,
                                              float* __restrict__ attn,
                                              bf16* __restrict__ ao) {
  // XCD-aware bijective swizzle (512 % 8 == 0)
  const int nbid = (blockIdx.x & 7) * 64 + (blockIdx.x >> 3);
  const int h  = nbid >> 5;
  const int ib = nbid & 31;                   // 64-row block index
  const int tid = threadIdx.x;
  const int c  = tid >> 6;                    // wave
  const int ri = c >> 1;                      // row-tile within block (0,1)
  const int cc = c & 1;                       // window half
  const int lane = tid & 63;
  const int l15 = lane & 15, l4 = lane >> 4;
  const int i0 = ib * 64 + ri * 32;
  const int lo_g = pad_lo(i0), hi_g = pad_hi(i0);

  __shared__ bf16 KP[4][2][32 * 64];          // 32 KB; f32 O-exchange after PV
  __shared__ unsigned short JFB[4][32 * 64];  // 16 KB raw-e bf16 ring
  __shared__ float sums[4][32];
  __shared__ float invL[2][32];

  short8 qf[2][2];
  #pragma unroll
  for (int fm = 0; fm < 2; ++fm)
    #pragma unroll
    for (int kg = 0; kg < 2; ++kg)
      qf[fm][kg] = *(const short8*)&q[((size_t)h * SEQ + i0 + fm * 16 + l15) * HD + kg * 32 + l4 * 8];

  const bf16* kbase = kkk + (size_t)h * SEQ * HD;
  const bf16* vbase = vT + (size_t)h * HD * SEQ;
  float* abase = attn + (size_t)(h * SEQ + i0) * WIN;

  // ---------------- phase 1: partial exp-sums (swapped QK), half-window per wave
  {
    constexpr int st[3] = {0, 32, 65};
    int lo = st[cc] > lo_g ? st[cc] : lo_g;
    int hi = st[cc + 1] < hi_g ? st[cc + 1] : hi_g;

    float psum[2] = {0.f, 0.f};
    if (lo < hi) {
      stage_kp(kbase, i0, lo, lane, KP[c][lo & 1]);
      for (int tt = lo; tt < hi; ++tt) {
        int nxt = (tt + 1 < hi) ? tt + 1 : tt;
        stage_kp(kbase, i0, nxt, lane, KP[c][(tt + 1) & 1]);
        asm volatile("s_waitcnt vmcnt(4)" ::: "memory");
        f32x4 sf[2][2] = {};
        qk_mfma_lds_sw(KP[c][tt & 1], qf, l15, l4, sf);
        const bool interior = (tt >= 1) && (tt <= 63) &&
                              (i0 + tt * 32 >= PAD) && (i0 + tt * 32 + 31 < PAD + SEQ);
        if (interior) {
          #pragma unroll
          for (int fj = 0; fj < 2; ++fj)
            #pragma unroll
            for (int r = 0; r < 4; ++r) {
              psum[0] += __builtin_amdgcn_exp2f(sf[fj][0][r]);
              psum[1] += __builtin_amdgcn_exp2f(sf[fj][1][r]);
            }
        } else {
          #pragma unroll
          for (int fj = 0; fj < 2; ++fj)
            #pragma unroll
            for (int r = 0; r < 4; ++r) {
              int jj = tt * 32 + fj * 16 + l4 * 4 + r;   // local j'
              int jp = i0 + jj;                          // absolute j'
              bool pad = (jp < PAD) || (jp >= PAD + SEQ);
              #pragma unroll
              for (int fi = 0; fi < 2; ++fi) {
                int iloc = fi * 16 + l15;
                float e = pad ? 1.0f : __builtin_amdgcn_exp2f(sf[fj][fi][r]);
                if ((unsigned)(jj - iloc) < (unsigned)WIN) psum[fi] += e;
              }
            }
        }
      }
    }
    float r0 = psum[0];
    r0 += __shfl_xor(r0, 16); r0 += __shfl_xor(r0, 32);
    float r1 = psum[1];
    r1 += __shfl_xor(r1, 16); r1 += __shfl_xor(r1, 32);
    if (lane < 32) {
      int i_abs = i0 + lane;
      float s = (lane < 16) ? r0 : r1;
      if (cc == 0) {
        int cl = i0 + lo_g * 32 - i_abs; if (cl < 0) cl = 0;
        int cr = i_abs + WIN - (i0 + hi_g * 32); if (cr < 0) cr = 0;
        s += (float)(cl + cr);                  // analytic all-pad contribution
      }
      sums[c][lane] = s;
    }
  }
  __syncthreads();
  if (tid < 64) {
    int rt = tid >> 5, row = tid & 31;
    invL[rt][row] = __builtin_amdgcn_rcpf(sums[rt * 2][row] + sums[rt * 2 + 1][row]);
  }
  __syncthreads();

  // per-lane flush inverses (row = s2*8 + (lane>>3), within row-tile ri)
  float invf[4];
  #pragma unroll
  for (int s2 = 0; s2 < 4; ++s2) invf[s2] = invL[ri][s2 * 8 + (lane >> 3)];

  // ---------------- phase 2: recompute QK, raw-e rebin, normalized flush, PV
  const int c0 = cc * 32, c1 = c0 + 32;
  unsigned short* JW = JFB[c];
  f32x4 oacc[2][4] = {};
  stage_kp(kbase, i0, c0, lane, KP[c][0]);     // c0 even -> buf 0
  for (int tt = c0; tt <= c1; ++tt) {
    short8 bv[4];
    if (tt > c0) {
      int jb = (tt - 1) * 32;
      #pragma unroll
      for (int nd = 0; nd < 4; ++nd)
        bv[nd] = *(const short8*)&vbase[(size_t)(nd * 16 + l15) * SEQ + jb + l4 * 8];
    }
    int nxt = (tt < c1) ? tt + 1 : tt;
    stage_kp(kbase, i0, nxt, lane, KP[c][(tt + 1) & 1]);
    // counted wait for stage(tt): younger = stores(t-1)[4]+bv[4]+stage(t+1)[4]
    if (tt == c0)          asm volatile("s_waitcnt vmcnt(4)" ::: "memory");
    else if (tt == c0 + 1) asm volatile("s_waitcnt vmcnt(8)" ::: "memory");
    else                   asm volatile("s_waitcnt vmcnt(12)" ::: "memory");

    const bool fp = (tt < lo_g) || (tt >= hi_g);   // all-pad tile: score==0 -> e=1
    f32x4 sf[2][2] = {};
    if (!fp) qk_mfma_lds(KP[c][tt & 1], qf, l15, l4, sf);

    // re-bin raw e (bf16) into j-aligned ring; 16B-group swizzle sg=(j6>>3)^(row&7)
    const bool allv = (i0 + tt * 32 >= PAD) && (i0 + tt * 32 + 31 < PAD + SEQ);
    #pragma unroll
    for (int fm = 0; fm < 2; ++fm)
      #pragma unroll
      for (int fn = 0; fn < 2; ++fn) {
        int J0 = tt * 32 + fn * 16 + l15;          // local j' (col)
        bool padc = fp || (!allv && ((i0 + J0 < PAD) || (i0 + J0 >= PAD + SEQ)));
        #pragma unroll
        for (int r = 0; r < 4; ++r) {
          int row = fm * 16 + l4 * 4 + r;          // local i
          float e = padc ? 1.0f : __builtin_amdgcn_exp2f(sf[fm][fn][r]);
          int j6 = (J0 - row) & 63;                // ring position
          int sg = (j6 >> 3) ^ (row & 7);
          JW[row * 64 + sg * 8 + (j6 & 7)] = __bfloat16_as_ushort(__float2bfloat16(e));
        }
      }

    if (tt > c0) {
      const int g = (tt - 1) & 1;                  // ring slot of completed j-tile
      const int Jb = (tt - 1) * 32;
      const int c8 = lane & 7;
      // flush: normalize raw e with invL at store time; full-128B-line stores
      #pragma unroll
      for (int s2 = 0; s2 < 4; ++s2) {
        int row = s2 * 8 + (lane >> 3);
        int sg = (g * 4 + (c8 >> 1)) ^ (row & 7);
        ushort4v uv = *(const ushort4v*)&JW[row * 64 + sg * 8 + (c8 & 1) * 4];
        f32x4 vv;
        #pragma unroll
        for (int e = 0; e < 4; ++e)
          vv[e] = __uint_as_float((unsigned)uv[e] << 16) * invf[s2];
        *(f32x4*)(abase + (size_t)row * WIN + Jb + c8 * 4) = vv;
      }
      // PV A-fragments: raw e, 16B contiguous per lane
      short8 af[2];
      #pragma unroll
      for (int fm = 0; fm < 2; ++fm) {
        int row = fm * 16 + l15;
        int sg = (g * 4 + l4) ^ (row & 7);
        af[fm] = *(const short8*)&JW[row * 64 + sg * 8];
      }
      __builtin_amdgcn_s_setprio(1);
      #pragma unroll
      for (int fm = 0; fm < 2; ++fm)
        #pragma unroll
        for (int nd = 0; nd < 4; ++nd)
          oacc[fm][nd] = __builtin_amdgcn_mfma_f32_16x16x32_bf16(af[fm], bv[nd], oacc[fm][nd], 0, 0, 0);
      __builtin_amdgcn_s_setprio(0);
    }
  }

  // ---------------- in-block O reduction in f32 via dead KP region; scale by invL
  __syncthreads();                              // all PV + staging drained
  float* OX = (float*)&KP[0][0][0];             // 32 KB = 4 waves x 2048 f32
  float* OW = OX + c * 2048;
  #pragma unroll
  for (int fm = 0; fm < 2; ++fm)
    #pragma unroll
    for (int nd = 0; nd < 4; ++nd)
      #pragma unroll
      for (int r = 0; r < 4; ++r)
        OW[(fm * 16 + l4 * 4 + r) * 64 + nd * 16 + l15] = oacc[fm][nd][r];
  __syncthreads();
  {
    int row64 = tid >> 2;                       // 0..63 row within block
    int rt = row64 >> 5, r32 = row64 & 31;
    int d0 = (tid & 3) * 16;
    const float* pA = OX + (rt * 2) * 2048 + r32 * 64;
    const float* pB = OX + (rt * 2 + 1) * 2048 + r32 * 64;
    float iv = invL[rt][r32];
    union { unsigned short u[16]; short8 v[2]; } o;
    #pragma unroll
    for (int e = 0; e < 16; ++e)
      o.u[e] = __bfloat16_as_ushort(__float2bfloat16((pA[d0 + e] + pB[d0 + e]) * iv));
    bf16* op = &ao[(size_t)(ib * 64 + row64) * DM + h * HD + d0];
    *(short8*)op = o.v[0];
    *(short8*)(op + 8) = o.v[1];
  }
}

// ---------------------------------------------------------------- K4: proj GEMM (64x128 tiles) -> d_out (f32)
__global__ __launch_bounds__(256) void k_gemm_proj(const bf16* __restrict__ A,
                                                   const bf16* __restrict__ B,
                                                   const float* __restrict__ bias,
                                                   float* __restrict__ out) {
  __shared__ bf16 As[64 * 64], Bs[128 * 64];
  const int tid = threadIdx.x, lane = tid & 63;
  const int wid = tid >> 6;
  const int l15 = lane & 15, l4 = lane >> 4;
  const int m0 = blockIdx.x * 64, n0 = blockIdx.y * 128;
  f32x4 acc[4][2] = {};
  gemm_core64(A, B, m0, n0, DM, tid, As, Bs, acc);
  #pragma unroll
  for (int im = 0; im < 4; ++im)
    #pragma unroll
    for (int in = 0; in < 2; ++in) {
      int col = n0 + wid * 32 + in * 16 + l15;
      float bval = bias[col];
      #pragma unroll
      for (int r = 0; r < 4; ++r) {
        int row = m0 + im * 16 + l4 * 4 + r;
        out[(size_t)row * DM + col] = acc[im][in][r] + bval;
      }
    }
}

// ---------------------------------------------------------------- launch
extern "C" void kernel_launch(void* const* d_in, const int* in_sizes, int n_in,
                              void* d_out, int out_size, void* d_ws, size_t ws_size,
                              hipStream_t stream) {
  (void)in_sizes; (void)n_in; (void)out_size; (void)ws_size;
  const float* x  = (const float*)d_in[0];
  const float* wq = (const float*)d_in[1];
  const float* bq = (const float*)d_in[2];
  const float* wp = (const float*)d_in[3];
  const float* bp = (const float*)d_in[4];
  float* out  = (float*)d_out;
  float* attn = out + (size_t)SEQ * DM;

  char* ws = (char*)d_ws;
  bf16* xb    = (bf16*)(ws + (size_t) 0);          // 4 MB  x bf16
  bf16* wqb   = (bf16*)(ws + ((size_t)4  << 20));  // 6 MB  w_qkv bf16
  bf16* wpb   = (bf16*)(ws + ((size_t)10 << 20));  // 2 MB  w_proj bf16
  bf16* qarr  = (bf16*)(ws + ((size_t)12 << 20));  // 4 MB  q [h][i][d] (scale*log2e folded)
  bf16* karr  = (bf16*)(ws + ((size_t)16 << 20));  // 4 MB  k [h][j][d]
  bf16* vt    = (bf16*)(ws + ((size_t)24 << 20));  // 4 MB  vT [h][d][j] (qkv epilogue)
  bf16* ao    = (bf16*)(ws + ((size_t)28 << 20));  // 4 MB  attn-out rows [i][h*64+d]

  k_cvt<<<dim3(1024), dim3(256), 0, stream>>>(x, wq, wp, xb, wqb, wpb);
  k_gemm_qkv<<<dim3(32, 24), dim3(256), 0, stream>>>(xb, wqb, bq, qarr, karr, vt);
  k_attn<<<dim3(512), dim3(256), 0, stream>>>(qarr, karr, vt, attn, ao);
  k_gemm_proj<<<dim3(32, 8), dim3(256), 0, stream>>>(ao, wpb, bp, out);
}

// Round 16
// 145.702 us; speedup vs baseline: 2.1510x; 1.0653x over previous
//
#include <hip/hip_runtime.h>
#include <hip/hip_bf16.h>

typedef __hip_bfloat16 bf16;
typedef __attribute__((ext_vector_type(8))) short short8;
typedef __attribute__((ext_vector_type(4))) float f32x4;
typedef __attribute__((ext_vector_type(4))) unsigned short ushort4v;

#define DEV static __device__ __forceinline__

static constexpr int SEQ = 2048;
static constexpr int DM  = 1024;
static constexpr int NH  = 16;
static constexpr int HD  = 64;
static constexpr int WIN = 2048;
static constexpr int PAD = 1024;   // WIN/2

// async global->LDS, 16B per lane; LDS dest = wave-uniform base + lane*16
DEV void async16(const void* g, void* l) {
  __builtin_amdgcn_global_load_lds(
      (__attribute__((address_space(1))) void*)(g),
      (__attribute__((address_space(3))) void*)(l), 16, 0, 0);
}

// ---------------------------------------------------------------- K0: f32 -> bf16 convert (x, w_qkv, w_proj)
__global__ __launch_bounds__(256) void k_cvt(const float* __restrict__ x,
                                             const float* __restrict__ wq,
                                             const float* __restrict__ wp,
                                             bf16* __restrict__ xb,
                                             bf16* __restrict__ wqb,
                                             bf16* __restrict__ wpb) {
  const int NX = SEQ * DM, NQ = 3 * DM * DM, NP = DM * DM;
  const int tot = (NX + NQ + NP) >> 2;
  const int stride = gridDim.x * 256;
  for (int i = blockIdx.x * 256 + threadIdx.x; i < tot; i += stride) {
    int e = i << 2;
    const float* s; bf16* d; int o;
    if (e < NX)            { s = x;  d = xb;  o = e; }
    else if (e < NX + NQ)  { s = wq; d = wqb; o = e - NX; }
    else                   { s = wp; d = wpb; o = e - NX - NQ; }
    float4 v = *(const float4*)(s + o);
    __align__(8) bf16 t4[4] = {__float2bfloat16(v.x), __float2bfloat16(v.y),
                               __float2bfloat16(v.z), __float2bfloat16(v.w)};
    *(uint2*)(d + o) = *(uint2*)t4;
  }
}

// ---------------------------------------------------------------- 64x128 GEMM core: C[m][n] = sum_k A[m][k]*B[n][k]
// 256 threads = 4 waves, each wave owns 64m x 32n (acc[4][2]); BK=64.
DEV void gemm_core64(const bf16* __restrict__ A, const bf16* __restrict__ B,
                     int m0, int n0, int K, int tid, bf16* As, bf16* Bs,
                     f32x4 (&acc)[4][2]) {
  const int lane = tid & 63, wid = tid >> 6;   // wid = n-group (0..3)
  const int l15 = lane & 15, l4 = lane >> 4;
  for (int k0 = 0; k0 < K; k0 += 64) {
    __syncthreads();
    #pragma unroll
    for (int it = 0; it < 2; ++it) {           // A: 64 rows
      int rb = it * 32 + wid * 8;
      int r  = rb + (lane >> 3);
      int c  = (lane & 7) * 8;
      async16(A + (size_t)(m0 + r) * K + k0 + c, As + rb * 64);
    }
    #pragma unroll
    for (int it = 0; it < 4; ++it) {           // B: 128 rows
      int rb = it * 32 + wid * 8;
      int r  = rb + (lane >> 3);
      int c  = (lane & 7) * 8;
      async16(B + (size_t)(n0 + r) * K + k0 + c, Bs + rb * 64);
    }
    asm volatile("s_waitcnt vmcnt(0)" ::: "memory");
    __syncthreads();
    #pragma unroll
    for (int kk = 0; kk < 2; ++kk) {
      short8 a[4], b[2];
      #pragma unroll
      for (int im = 0; im < 4; ++im)
        a[im] = *(const short8*)(As + (im * 16 + l15) * 64 + kk * 32 + l4 * 8);
      #pragma unroll
      for (int in = 0; in < 2; ++in)
        b[in] = *(const short8*)(Bs + (wid * 32 + in * 16 + l15) * 64 + kk * 32 + l4 * 8);
      #pragma unroll
      for (int im = 0; im < 4; ++im)
        #pragma unroll
        for (int in = 0; in < 2; ++in)
          acc[im][in] = __builtin_amdgcn_mfma_f32_16x16x32_bf16(a[im], b[in], acc[im][in], 0, 0, 0);
    }
  }
}

// ---------------------------------------------------------------- K1: qkv GEMM (64x128 tiles) + scatter to q/k/vT
__global__ __launch_bounds__(256) void k_gemm_qkv(const bf16* __restrict__ A,
                                                  const bf16* __restrict__ B,
                                                  const float* __restrict__ bias,
                                                  bf16* __restrict__ qo,
                                                  bf16* __restrict__ ko,
                                                  bf16* __restrict__ vt) {
  __shared__ bf16 As[64 * 64], Bs[128 * 64];
  const int tid = threadIdx.x, lane = tid & 63;
  const int wid = tid >> 6;
  const int l15 = lane & 15, l4 = lane >> 4;
  const int m0 = blockIdx.x * 64, n0 = blockIdx.y * 128;
  f32x4 acc[4][2] = {};
  gemm_core64(A, B, m0, n0, DM, tid, As, Bs, acc);
  #pragma unroll
  for (int im = 0; im < 4; ++im)
    #pragma unroll
    for (int in = 0; in < 2; ++in) {
      int col = n0 + wid * 32 + in * 16 + l15;
      float bval = bias[col];
      int t = col >> 10, h = (col >> 6) & 15, dd = col & 63;
      int row0 = m0 + im * 16 + l4 * 4;
      if (t == 2) {
        // v transposed directly: vT[h][dd][j], 4 consecutive j -> one 8B store
        __align__(8) bf16 t4[4];
        #pragma unroll
        for (int r = 0; r < 4; ++r)
          t4[r] = __float2bfloat16(acc[im][in][r] + bval);
        *(uint2*)&vt[((size_t)h * HD + dd) * SEQ + row0] = *(uint2*)t4;
      } else {
        #pragma unroll
        for (int r = 0; r < 4; ++r) {
          float v = acc[im][in][r] + bval;
          size_t idx = ((size_t)h * SEQ + row0 + r) * HD + dd;
          // q folded with hd^-0.5 * log2(e) so scores feed exp2 directly
          if (t == 0) qo[idx] = __float2bfloat16(v * 0.18033688011112042f);
          else        ko[idx] = __float2bfloat16(v);
        }
      }
    }
}

// ---------------------------------------------------------------- attn helpers
DEV void stage_kp(const bf16* kbase, int i0, int tt, int lane, bf16* dst) {
  #pragma unroll
  for (int it = 0; it < 4; ++it) {
    int r  = it * 8 + (lane >> 3);
    int cg = lane & 7;
    int jp = i0 + tt * 32 + r;                 // absolute j'
    int krow = jp - PAD;                       // clamp; pad handled analytically
    krow = krow < 0 ? 0 : (krow > SEQ - 1 ? SEQ - 1 : krow);
    int sc = (cg ^ (r & 7)) * 8;               // pre-swizzled global source
    async16(kbase + (size_t)krow * HD + sc, dst + it * 8 * 64);
  }
}

// LDS K -> MFMA, unswapped: sf[fm][fn]: col=j'(l15), row=i(l4*4+r)
DEV void qk_mfma_lds(const bf16* KPb, const short8 (&qf)[2][2], int l15, int l4,
                     f32x4 (&sf)[2][2]) {
  __builtin_amdgcn_s_setprio(1);
  #pragma unroll
  for (int kg = 0; kg < 2; ++kg) {
    short8 kfr[2];
    #pragma unroll
    for (int fn = 0; fn < 2; ++fn) {
      int jl = fn * 16 + l15;
      int pg = (kg * 4 + l4) ^ (jl & 7);
      kfr[fn] = *(const short8*)&KPb[jl * 64 + pg * 8];
    }
    #pragma unroll
    for (int fm = 0; fm < 2; ++fm)
      #pragma unroll
      for (int fn = 0; fn < 2; ++fn)
        sf[fm][fn] = __builtin_amdgcn_mfma_f32_16x16x32_bf16(qf[fm][kg], kfr[fn], sf[fm][fn], 0, 0, 0);
  }
  __builtin_amdgcn_s_setprio(0);
}

// swapped variant (phase 1): sf[fj][fi]: col=i(l15), row=j'(l4*4+r)
DEV void qk_mfma_lds_sw(const bf16* KPb, const short8 (&qf)[2][2], int l15, int l4,
                        f32x4 (&sf)[2][2]) {
  __builtin_amdgcn_s_setprio(1);
  #pragma unroll
  for (int kg = 0; kg < 2; ++kg) {
    short8 kfr[2];
    #pragma unroll
    for (int fj = 0; fj < 2; ++fj) {
      int jl = fj * 16 + l15;
      int pg = (kg * 4 + l4) ^ (jl & 7);
      kfr[fj] = *(const short8*)&KPb[jl * 64 + pg * 8];
    }
    #pragma unroll
    for (int fj = 0; fj < 2; ++fj)
      #pragma unroll
      for (int fi = 0; fi < 2; ++fi)
        sf[fj][fi] = __builtin_amdgcn_mfma_f32_16x16x32_bf16(kfr[fj], qf[fi][kg], sf[fj][fi], 0, 0, 0);
  }
  __builtin_amdgcn_s_setprio(0);
}

DEV int pad_lo(int i0) { int d = PAD - i0; return d <= 0 ? 0 : (d >> 5); }
DEV int pad_hi(int i0) { int t = ((PAD + SEQ - 1 - i0) >> 5) + 1; return t > 65 ? 65 : t; }

// ---------------------------------------------------------------- K2: merged attn (sum pass + normalize/flush/PV pass)
// block = (h, i0) via XCD-chunked swizzle; 4 chunk-waves.
__global__ __launch_bounds__(256) void k_attn(const bf16* __restrict__ q,
                                              const bf16* __restrict__ kkk,
                                              const bf16* __restrict__ vT,
                                              float* __restrict__ attn,
                                              bf16* __restrict__ ao) {
  // XCD-aware bijective swizzle (1024 % 8 == 0): each XCD gets contiguous work
  const int wgid = (blockIdx.x & 7) * 128 + (blockIdx.x >> 3);
  const int h  = wgid >> 6;
  const int i0 = (wgid & 63) << 5;
  const int tid = threadIdx.x;
  const int c = tid >> 6;                     // wave = chunk
  const int lane = tid & 63;
  const int l15 = lane & 15, l4 = lane >> 4;
  const int lo_g = pad_lo(i0), hi_g = pad_hi(i0);

  __shared__ bf16 KP[4][2][32 * 64];          // 32 KB; f32 O-exchange after PV
  __shared__ unsigned short JFB[4][32 * 64];  // 16 KB raw-e bf16 ring, 16B-group XOR swizzle
  __shared__ float sums[4][32];
  __shared__ float invL[32];

  short8 qf[2][2];
  #pragma unroll
  for (int fm = 0; fm < 2; ++fm)
    #pragma unroll
    for (int kg = 0; kg < 2; ++kg)
      qf[fm][kg] = *(const short8*)&q[((size_t)h * SEQ + i0 + fm * 16 + l15) * HD + kg * 32 + l4 * 8];

  const bf16* kbase = kkk + (size_t)h * SEQ * HD;
  const bf16* vbase = vT + (size_t)h * HD * SEQ;
  float* abase = attn + (size_t)(h * SEQ + i0) * WIN;

  const int c0 = c * 16, c1 = c0 + 16;

  // ---------------- phase 1: partial exp-sums (swapped QK)
  {
    constexpr int st[5] = {0, 16, 32, 48, 65};
    int lo = st[c] > lo_g ? st[c] : lo_g;
    int hi = st[c + 1] < hi_g ? st[c + 1] : hi_g;

    float psum[2] = {0.f, 0.f};
    if (lo < hi) {
      stage_kp(kbase, i0, lo, lane, KP[c][lo & 1]);
      for (int tt = lo; tt < hi; ++tt) {
        int nxt = (tt + 1 < hi) ? tt + 1 : tt;
        stage_kp(kbase, i0, nxt, lane, KP[c][(tt + 1) & 1]);
        asm volatile("s_waitcnt vmcnt(4)" ::: "memory");
        f32x4 sf[2][2] = {};
        qk_mfma_lds_sw(KP[c][tt & 1], qf, l15, l4, sf);
        const bool interior = (tt >= 1) && (tt <= 63) &&
                              (i0 + tt * 32 >= PAD) && (i0 + tt * 32 + 31 < PAD + SEQ);
        if (interior) {
          #pragma unroll
          for (int fj = 0; fj < 2; ++fj)
            #pragma unroll
            for (int r = 0; r < 4; ++r) {
              psum[0] += __builtin_amdgcn_exp2f(sf[fj][0][r]);
              psum[1] += __builtin_amdgcn_exp2f(sf[fj][1][r]);
            }
        } else {
          #pragma unroll
          for (int fj = 0; fj < 2; ++fj)
            #pragma unroll
            for (int r = 0; r < 4; ++r) {
              int jj = tt * 32 + fj * 16 + l4 * 4 + r;   // local j'
              int jp = i0 + jj;                          // absolute j'
              bool pad = (jp < PAD) || (jp >= PAD + SEQ);
              #pragma unroll
              for (int fi = 0; fi < 2; ++fi) {
                int iloc = fi * 16 + l15;
                float e = pad ? 1.0f : __builtin_amdgcn_exp2f(sf[fj][fi][r]);
                if ((unsigned)(jj - iloc) < (unsigned)WIN) psum[fi] += e;
              }
            }
        }
      }
    }
    // pre-issue phase-2's first K tile now: its latency hides under the
    // reduce + barrier (per-wave buffer; phase-1 LDS reads already retired)
    stage_kp(kbase, i0, c0, lane, KP[c][0]);   // c0 even -> buf 0

    float r0 = psum[0];
    r0 += __shfl_xor(r0, 16); r0 += __shfl_xor(r0, 32);
    float r1 = psum[1];
    r1 += __shfl_xor(r1, 16); r1 += __shfl_xor(r1, 32);
    if (lane < 32) {
      int i_abs = i0 + lane;
      float s = (lane < 16) ? r0 : r1;
      if (c == 0) {
        int cl = i0 + lo_g * 32 - i_abs; if (cl < 0) cl = 0;
        int cr = i_abs + WIN - (i0 + hi_g * 32); if (cr < 0) cr = 0;
        s += (float)(cl + cr);                  // analytic all-pad contribution
      }
      sums[c][lane] = s;
    }
  }
  __syncthreads();
  if (tid < 32)
    invL[tid] = __builtin_amdgcn_rcpf(sums[0][tid] + sums[1][tid] +
                                      sums[2][tid] + sums[3][tid]);
  __syncthreads();

  // per-lane flush inverses (row = s2*8 + (lane>>3))
  float invf[4];
  #pragma unroll
  for (int s2 = 0; s2 < 4; ++s2) invf[s2] = invL[s2 * 8 + (lane >> 3)];

  // ---------------- phase 2: recompute QK, raw-e rebin, normalized flush, PV
  unsigned short* JW = JFB[c];
  f32x4 oacc[2][4] = {};
  for (int tt = c0; tt <= c1; ++tt) {
    short8 bv[4];
    if (tt > c0) {
      int jb = (tt - 1) * 32;
      #pragma unroll
      for (int nd = 0; nd < 4; ++nd)
        bv[nd] = *(const short8*)&vbase[(size_t)(nd * 16 + l15) * SEQ + jb + l4 * 8];
    }
    int nxt = (tt < c1) ? tt + 1 : tt;
    stage_kp(kbase, i0, nxt, lane, KP[c][(tt + 1) & 1]);
    // counted wait for stage(tt): younger = stores(t-1)[4]+bv[4]+stage(t+1)[4]
    if (tt == c0)          asm volatile("s_waitcnt vmcnt(4)" ::: "memory");
    else if (tt == c0 + 1) asm volatile("s_waitcnt vmcnt(8)" ::: "memory");
    else                   asm volatile("s_waitcnt vmcnt(12)" ::: "memory");

    const bool fp = (tt < lo_g) || (tt >= hi_g);   // all-pad tile: score==0 -> e=1
    f32x4 sf[2][2] = {};
    if (!fp) qk_mfma_lds(KP[c][tt & 1], qf, l15, l4, sf);

    // re-bin raw e (bf16) into j-aligned ring; 16B-group swizzle sg=(j6>>3)^(row&7)
    const bool allv = (i0 + tt * 32 >= PAD) && (i0 + tt * 32 + 31 < PAD + SEQ);
    #pragma unroll
    for (int fm = 0; fm < 2; ++fm)
      #pragma unroll
      for (int fn = 0; fn < 2; ++fn) {
        int J0 = tt * 32 + fn * 16 + l15;          // local j' (col)
        bool padc = fp || (!allv && ((i0 + J0 < PAD) || (i0 + J0 >= PAD + SEQ)));
        #pragma unroll
        for (int r = 0; r < 4; ++r) {
          int row = fm * 16 + l4 * 4 + r;          // local i
          float e = padc ? 1.0f : __builtin_amdgcn_exp2f(sf[fm][fn][r]);
          int j6 = (J0 - row) & 63;                // ring position
          int sg = (j6 >> 3) ^ (row & 7);
          JW[row * 64 + sg * 8 + (j6 & 7)] = __bfloat16_as_ushort(__float2bfloat16(e));
        }
      }

    if (tt > c0) {
      const int g = (tt - 1) & 1;                  // ring slot of completed j-tile
      const int Jb = (tt - 1) * 32;
      const int c8 = lane & 7;
      // flush: normalize raw e with invL at store time; full-128B-line stores
      #pragma unroll
      for (int s2 = 0; s2 < 4; ++s2) {
        int row = s2 * 8 + (lane >> 3);
        int sg = (g * 4 + (c8 >> 1)) ^ (row & 7);
        ushort4v uv = *(const ushort4v*)&JW[row * 64 + sg * 8 + (c8 & 1) * 4];
        f32x4 vv;
        #pragma unroll
        for (int e = 0; e < 4; ++e)
          vv[e] = __uint_as_float((unsigned)uv[e] << 16) * invf[s2];
        *(f32x4*)(abase + (size_t)row * WIN + Jb + c8 * 4) = vv;
      }
      // PV A-fragments: raw e, 16B contiguous per lane
      short8 af[2];
      #pragma unroll
      for (int fm = 0; fm < 2; ++fm) {
        int row = fm * 16 + l15;
        int sg = (g * 4 + l4) ^ (row & 7);
        af[fm] = *(const short8*)&JW[row * 64 + sg * 8];
      }
      __builtin_amdgcn_s_setprio(1);
      #pragma unroll
      for (int fm = 0; fm < 2; ++fm)
        #pragma unroll
        for (int nd = 0; nd < 4; ++nd)
          oacc[fm][nd] = __builtin_amdgcn_mfma_f32_16x16x32_bf16(af[fm], bv[nd], oacc[fm][nd], 0, 0, 0);
      __builtin_amdgcn_s_setprio(0);
    }
  }

  // ---------------- in-block O reduction in f32 via dead KP region; scale by invL
  __syncthreads();                              // all PV + staging drained
  float* OX = (float*)&KP[0][0][0];             // 32 KB = 4 waves x 2048 f32
  float* OW = OX + c * 2048;
  #pragma unroll
  for (int fm = 0; fm < 2; ++fm)
    #pragma unroll
    for (int nd = 0; nd < 4; ++nd)
      #pragma unroll
      for (int r = 0; r < 4; ++r)
        OW[(fm * 16 + l4 * 4 + r) * 64 + nd * 16 + l15] = oacc[fm][nd][r];
  __syncthreads();
  {
    int row = tid >> 3;
    int d0 = (tid & 7) * 8;
    float iv = invL[row];
    union { unsigned short u[8]; short8 v; } o;
    #pragma unroll
    for (int e = 0; e < 8; ++e) {
      int idx = row * 64 + d0 + e;
      float s = (OX[idx] + OX[2048 + idx] + OX[4096 + idx] + OX[6144 + idx]) * iv;
      o.u[e] = __bfloat16_as_ushort(__float2bfloat16(s));
    }
    *(short8*)&ao[(size_t)(i0 + row) * DM + h * HD + d0] = o.v;
  }
}

// ---------------------------------------------------------------- K4: proj GEMM (64x128 tiles) -> d_out (f32)
__global__ __launch_bounds__(256) void k_gemm_proj(const bf16* __restrict__ A,
                                                   const bf16* __restrict__ B,
                                                   const float* __restrict__ bias,
                                                   float* __restrict__ out) {
  __shared__ bf16 As[64 * 64], Bs[128 * 64];
  const int tid = threadIdx.x, lane = tid & 63;
  const int wid = tid >> 6;
  const int l15 = lane & 15, l4 = lane >> 4;
  const int m0 = blockIdx.x * 64, n0 = blockIdx.y * 128;
  f32x4 acc[4][2] = {};
  gemm_core64(A, B, m0, n0, DM, tid, As, Bs, acc);
  #pragma unroll
  for (int im = 0; im < 4; ++im)
    #pragma unroll
    for (int in = 0; in < 2; ++in) {
      int col = n0 + wid * 32 + in * 16 + l15;
      float bval = bias[col];
      #pragma unroll
      for (int r = 0; r < 4; ++r) {
        int row = m0 + im * 16 + l4 * 4 + r;
        out[(size_t)row * DM + col] = acc[im][in][r] + bval;
      }
    }
}

// ---------------------------------------------------------------- launch
extern "C" void kernel_launch(void* const* d_in, const int* in_sizes, int n_in,
                              void* d_out, int out_size, void* d_ws, size_t ws_size,
                              hipStream_t stream) {
  (void)in_sizes; (void)n_in; (void)out_size; (void)ws_size;
  const float* x  = (const float*)d_in[0];
  const float* wq = (const float*)d_in[1];
  const float* bq = (const float*)d_in[2];
  const float* wp = (const float*)d_in[3];
  const float* bp = (const float*)d_in[4];
  float* out  = (float*)d_out;
  float* attn = out + (size_t)SEQ * DM;

  char* ws = (char*)d_ws;
  bf16* xb    = (bf16*)(ws + (size_t) 0);          // 4 MB  x bf16
  bf16* wqb   = (bf16*)(ws + ((size_t)4  << 20));  // 6 MB  w_qkv bf16
  bf16* wpb   = (bf16*)(ws + ((size_t)10 << 20));  // 2 MB  w_proj bf16
  bf16* qarr  = (bf16*)(ws + ((size_t)12 << 20));  // 4 MB  q [h][i][d] (scale*log2e folded)
  bf16* karr  = (bf16*)(ws + ((size_t)16 << 20));  // 4 MB  k [h][j][d]
  bf16* vt    = (bf16*)(ws + ((size_t)24 << 20));  // 4 MB  vT [h][d][j] (qkv epilogue)
  bf16* ao    = (bf16*)(ws + ((size_t)28 << 20));  // 4 MB  attn-out rows [i][h*64+d]

  k_cvt<<<dim3(1024), dim3(256), 0, stream>>>(x, wq, wp, xb, wqb, wpb);
  k_gemm_qkv<<<dim3(32, 24), dim3(256), 0, stream>>>(xb, wqb, bq, qarr, karr, vt);
  k_attn<<<dim3(1024), dim3(256), 0, stream>>>(qarr, karr, vt, attn, ao);
  k_gemm_proj<<<dim3(32, 8), dim3(256), 0, stream>>>(ao, wpb, bp, out);
}